// Round 6
// baseline (293.447 us; speedup 1.0000x reference)
//
#include <hip/hip_runtime.h>
#include <stdint.h>

#define GW 1024
#define GH 1024
#define NPIX (GW*GH)
#define CAP 8192        // max candidates (list/adj capacity)
#define KCAP 4096       // max final keeps held for output ordering
#define ADJ_STRIDE 48   // u16: [0]=n3|n<<6|high<<12, [1..n]= nid | nbrHigh<<15
#define TW 128
#define TH 16
// mm: [0]=cand count [1]=rmin [2]=rmax [3]=bmax [8]=ticket_resid [9]=ticket_conv

// residual map + per-block min/max partials + last-block tail reduction
__global__ __launch_bounds__(256) void k_resid(const float4* __restrict__ x1,
                        const float4* __restrict__ x2,
                        const float4* __restrict__ x3, float4* __restrict__ r,
                        float2* __restrict__ pmm, unsigned int* __restrict__ mm) {
  const int N4 = NPIX / 4;
  int t = blockIdx.x * blockDim.x + threadIdx.x;
  float4 s1 = make_float4(0.f,0.f,0.f,0.f);
  float4 s2 = make_float4(0.f,0.f,0.f,0.f);
#pragma unroll
  for (int c = 0; c < 8; ++c) {
    float4 a = x1[c*N4 + t];
    float4 b = x2[c*N4 + t];
    float4 d = x3[c*N4 + t];
    s1.x += fabsf(a.x-b.x); s1.y += fabsf(a.y-b.y);
    s1.z += fabsf(a.z-b.z); s1.w += fabsf(a.w-b.w);
    s2.x += fabsf(b.x-d.x); s2.y += fabsf(b.y-d.y);
    s2.z += fabsf(b.z-d.z); s2.w += fabsf(b.w-d.w);
  }
  float4 rv = make_float4((s1.x+s2.x)*0.5f, (s1.y+s2.y)*0.5f,
                          (s1.z+s2.z)*0.5f, (s1.w+s2.w)*0.5f);
  r[t] = rv;
  float mn = fminf(fminf(rv.x,rv.y), fminf(rv.z,rv.w));
  float mx = fmaxf(fmaxf(rv.x,rv.y), fmaxf(rv.z,rv.w));
#pragma unroll
  for (int o = 32; o > 0; o >>= 1) {
    mn = fminf(mn, __shfl_down(mn, o));
    mx = fmaxf(mx, __shfl_down(mx, o));
  }
  __shared__ float smn[4], smx[4];
  __shared__ bool isLast;
  int wid = threadIdx.x >> 6;
  if ((threadIdx.x & 63) == 0) { smn[wid] = mn; smx[wid] = mx; }
  __syncthreads();
  if (threadIdx.x == 0) {
    float a = fminf(fminf(smn[0], smn[1]), fminf(smn[2], smn[3]));
    float b = fmaxf(fmaxf(smx[0], smx[1]), fmaxf(smx[2], smx[3]));
    pmm[blockIdx.x] = make_float2(a, b);
    __threadfence();
    unsigned int tk = atomicAdd(&mm[8], 1u);
    isLast = (tk == gridDim.x - 1);
  }
  __syncthreads();
  if (isLast) {
    __threadfence();
    int tid = threadIdx.x;
    float2 p = pmm[tid];
    mn = p.x; mx = p.y;
#pragma unroll
    for (int i = 1; i < 4; ++i) {
      float2 q = pmm[tid + 256*i];
      mn = fminf(mn, q.x); mx = fmaxf(mx, q.y);
    }
#pragma unroll
    for (int o = 32; o > 0; o >>= 1) {
      mn = fminf(mn, __shfl_down(mn, o));
      mx = fmaxf(mx, __shfl_down(mx, o));
    }
    if ((tid & 63) == 0) { smn[tid>>6] = mn; smx[tid>>6] = mx; }
    __syncthreads();
    if (tid == 0) {
      float a = fminf(fminf(smn[0], smn[1]), fminf(smn[2], smn[3]));
      float b = fmaxf(fmaxf(smx[0], smx[1]), fmaxf(smx[2], smx[3]));
      mm[1] = __float_as_uint(a);
      mm[2] = __float_as_uint(b);
    }
  }
}

// fused normalize + y-interp + x-interp over TWxTH tiles with halo in LDS.
// per-output arithmetic identical to the separate convy/convx kernels.
__global__ __launch_bounds__(256) void k_conv(const float* __restrict__ r,
                        float* __restrict__ B, float* __restrict__ pconv,
                        unsigned int* __restrict__ mm) {
  __shared__ float sN[TH+4][TW+4];
  __shared__ float sA[TH][TW+4];
  __shared__ float smx[4];
  __shared__ bool isLast;
  int x0 = blockIdx.x * TW, y0 = blockIdx.y * TH;
  int tid = threadIdx.x;
  float rmin = __uint_as_float(mm[1]);
  float denom = __uint_as_float(mm[2]) - rmin + 1e-6f;
  const float offs[4] = {-1.5f, -0.5f, 0.5f, 1.5f};
  // stage + normalize (TH+4)x(TW+4) (edge rows/cols duplicated via clamp)
  for (int i = tid; i < (TH+4)*(TW+4); i += 256) {
    int row = i / (TW+4), col = i - row*(TW+4);
    int gy = min(max(y0 - 2 + row, 0), GH-1);
    int gx = min(max(x0 - 2 + col, 0), GW-1);
    sN[row][col] = (r[gy*GW + gx] - rmin) / denom;
  }
  __syncthreads();
  // A tile: y-taps, absolute-y weights (exact _interp1d semantics)
  for (int i = tid; i < TH*(TW+4); i += 256) {
    int ty = i / (TW+4), c0 = i - ty*(TW+4);
    int y = y0 + ty;
    float a = 0.f, b = 0.f;
#pragma unroll
    for (int k = 0; k < 4; ++k) {
      float c = (float)y + offs[k];
      bool valid = (c >= -1.0f) && (c <= (float)GH);
      float cc = fminf(fmaxf(c, 0.0f), (float)(GH - 1));
      int lo = (int)floorf(cc);
      int hi = min(lo + 1, GH - 1);
      float frac = cc - (float)lo;
      float w0 = valid ? 1.0f - frac : 0.0f;
      float w1 = valid ? frac : 0.0f;
      a += sN[lo - (y0-2)][c0] * w0;
      b += sN[hi - (y0-2)][c0] * w1;
    }
    sA[ty][c0] = a + b;
  }
  __syncthreads();
  // B: x-taps; thread -> column x0+(tid&127), rows (tid>>7)*8 .. +7
  int tx = tid & 127;
  int tyb = (tid >> 7) * 8;
  int x = x0 + tx;
  int xl[4], xh[4]; float w0x[4], w1x[4];
#pragma unroll
  for (int k = 0; k < 4; ++k) {
    float c = (float)x + offs[k];
    bool valid = (c >= -1.0f) && (c <= (float)GW);
    float cc = fminf(fmaxf(c, 0.0f), (float)(GW - 1));
    int lo = (int)floorf(cc);
    int hi = min(lo + 1, GW - 1);
    float frac = cc - (float)lo;
    w0x[k] = valid ? 1.0f - frac : 0.0f;
    w1x[k] = valid ? frac : 0.0f;
    xl[k] = lo - (x0-2); xh[k] = hi - (x0-2);
  }
  float mxv = 0.0f;   // B >= 0 always
#pragma unroll
  for (int q = 0; q < 8; ++q) {
    int ty = tyb + q;
    float a = 0.f, b = 0.f;
#pragma unroll
    for (int k = 0; k < 4; ++k) {
      a += sA[ty][xl[k]] * w0x[k];
      b += sA[ty][xh[k]] * w1x[k];
    }
    float v = (a + b) * 0.0625f;   // /16 exact
    B[(size_t)(y0+ty)*GW + x] = v;
    mxv = fmaxf(mxv, v);
  }
#pragma unroll
  for (int o = 32; o > 0; o >>= 1) mxv = fmaxf(mxv, __shfl_down(mxv, o));
  if ((tid & 63) == 0) smx[tid>>6] = mxv;
  __syncthreads();
  int nblk = gridDim.x * gridDim.y;
  int bid = blockIdx.y * gridDim.x + blockIdx.x;
  if (tid == 0) {
    pconv[bid] = fmaxf(fmaxf(smx[0], smx[1]), fmaxf(smx[2], smx[3]));
    __threadfence();
    unsigned int tk = atomicAdd(&mm[9], 1u);
    isLast = (tk == (unsigned int)(nblk - 1));
  }
  __syncthreads();
  if (isLast) {
    __threadfence();
    float mx = pconv[tid];
    mx = fmaxf(mx, pconv[tid + 256]);
#pragma unroll
    for (int o = 32; o > 0; o >>= 1) mx = fmaxf(mx, __shfl_down(mx, o));
    if ((tid & 63) == 0) smx[tid>>6] = mx;
    __syncthreads();
    if (tid == 0)
      mm[3] = __float_as_uint(fmaxf(fmaxf(smx[0], smx[1]), fmaxf(smx[2], smx[3])));
  }
}

// candidate compaction (<=1 atomic per block); ids arbitrary order.
// list[id]=pos, scores[id]=s, map[pos]=id (else ~0)
__global__ void k_cand(const float4* __restrict__ B, uint4* __restrict__ map,
                       unsigned int* __restrict__ list, float* __restrict__ scores,
                       unsigned int* __restrict__ mm) {
  int t = blockIdx.x * 256 + threadIdx.x;
  int tid = threadIdx.x;
  float bmax = __uint_as_float(mm[3]);
  float dv = bmax + 1e-6f;
  float4 b = B[t];
  float l[4] = { b.x/dv, b.y/dv, b.z/dv, b.w/dv };
  unsigned int flags = 0; int cnt = 0;
#pragma unroll
  for (int k = 0; k < 4; ++k) {
    float s = l[k];
    if (s > 0.90f && !(s == 0.95f)) { flags |= 1u << k; cnt++; }
  }
  __shared__ unsigned int sscan[256];
  __shared__ unsigned int sbase;
  sscan[tid] = (unsigned int)cnt;
  __syncthreads();
  for (int off = 1; off < 256; off <<= 1) {
    unsigned int v = sscan[tid];
    unsigned int a = (tid >= off) ? sscan[tid - off] : 0u;
    __syncthreads();
    sscan[tid] = v + a;
    __syncthreads();
  }
  if (tid == 255) {
    unsigned int tot = sscan[255];
    if (tot) sbase = atomicAdd(&mm[0], tot);
  }
  __syncthreads();
  unsigned int mv[4] = { ~0u, ~0u, ~0u, ~0u };
  if (flags) {
    unsigned int o = sbase + sscan[tid] - (unsigned int)cnt;
    unsigned int base4 = (unsigned int)t * 4u;
#pragma unroll
    for (int k = 0; k < 4; ++k) {
      if ((flags >> k) & 1u) {
        if (o < CAP) { list[o] = base4 + (unsigned int)k; scores[o] = l[k]; mv[k] = o; }
        o++;
      }
    }
  }
  map[t] = make_uint4(mv[0], mv[1], mv[2], mv[3]);
}

// single block: adjacency build + fused ABC fixed-point NMS + ordered output.
// st bits: 1=AB_DEC 2=AB_KEPT 4=C_DEC 8=C_KEPT 16=LOW
__global__ __launch_bounds__(1024) void k_final(const unsigned int* __restrict__ list,
                                                const float* __restrict__ scores,
                                                const unsigned int* __restrict__ map,
                                                const unsigned int* __restrict__ mm,
                                                unsigned short* __restrict__ adj,
                                                float* __restrict__ out, int nrows) {
  __shared__ unsigned char st[CAP];
  __shared__ unsigned short act[2][CAP];
  __shared__ unsigned long long skeys[KCAP];
  __shared__ unsigned int s_cnt[2];
  __shared__ unsigned int s_k;
  const int tid = threadIdx.x;
  int M = (int)min(mm[0], (unsigned int)CAP);

  // ---- adjacency: outranking conflicting neighbors (inter>=3 first).
  // priority: score desc, pos asc; scores>=0 so float order == uint-bit order.
  for (int r = tid; r < M; r += 1024) {
    unsigned int pos = list[r];
    float s = scores[r];
    unsigned int sb = __float_as_uint(s);
    unsigned int high = (s > 0.95f) ? 1u : 0u;
    int y = (int)(pos >> 10), x = (int)(pos & 1023);
    int n = 0, n3 = 0;
    unsigned short* row = adj + (size_t)r * ADJ_STRIDE;
#pragma unroll
    for (int pass = 0; pass < 2; ++pass) {
      for (int dy = -3; dy <= 3; ++dy) {
        int ady = dy < 0 ? -dy : dy;
        int wy = 4 - ady;
        int ny = y + dy;
        if ((unsigned)ny >= (unsigned)GH) continue;
        for (int dx = -3; dx <= 3; ++dx) {
          if ((dx | dy) == 0) continue;
          int adx = dx < 0 ? -dx : dx;
          int prod = (4 - adx) * wy;
          if (prod < 2) continue;
          if ((pass == 0) != (prod >= 3)) continue;
          int nx = x + dx;
          if ((unsigned)nx >= (unsigned)GW) continue;
          unsigned int npix = (unsigned int)(ny*GW + nx);
          unsigned int nid = map[npix];
          if (nid == ~0u) continue;
          float ns = scores[nid];
          unsigned int nsb = __float_as_uint(ns);
          if (nsb > sb || (nsb == sb && npix < pos)) {
            unsigned int nh = (ns > 0.95f) ? 1u : 0u;
            row[1 + n] = (unsigned short)(nid | (nh << 15));
            n++;
            if (pass == 0) n3++;
          }
        }
      }
    }
    row[0] = (unsigned short)(n3 | (n << 6) | (high << 12));
  }
  for (int i = tid; i < CAP; i += 1024) st[i] = 0;
  for (int i = tid; i < M; i += 1024) act[0][i] = (unsigned short)i;
  if (tid == 0) { s_cnt[0] = (unsigned int)M; s_cnt[1] = 0; s_k = 0; }
  __syncthreads();   // adj writes by this block drained before reads

  // ---- one fixed point for stages A (highs), B (lows, n3 prefix), C (chained)
  int cur = 0;
  for (int round = 0; round < CAP; ++round) {
    unsigned int cnt = s_cnt[cur];
    if (cnt == 0) break;
    for (unsigned int i = tid; i < cnt; i += 1024) {
      int r = act[cur][i];
      const unsigned short* row = adj + (size_t)r * ADJ_STRIDE;
      unsigned int hdr = row[0];
      unsigned int high = (hdr >> 12) & 1u;
      int nAll = (int)((hdr >> 6) & 63u);
      int n3 = (int)(hdr & 63u);
      if (high) {
        bool sup = false, und = false;
        for (int k = 1; k <= nAll; ++k) {
          unsigned int e = row[k];
          if (!(e >> 15)) continue;               // same band (high) only
          unsigned char ps = st[e & 0x1FFFu];
          if (ps & 2) { sup = true; break; }
          if (!(ps & 1)) und = true;
        }
        if (sup) st[r] = 1;
        else if (!und) st[r] = 3;
        else { unsigned int j = atomicAdd(&s_cnt[cur^1],1u); act[cur^1][j] = (unsigned short)r; }
      } else {
        unsigned char cs = st[r];
        if (!(cs & 1)) {
          // B step: low-band outranking nbrs within n3 prefix
          bool sup = false, und = false;
          for (int k = 1; k <= n3; ++k) {
            unsigned int e = row[k];
            if (e >> 15) continue;
            unsigned char ps = st[e & 0x1FFFu];
            if (ps & 2) { sup = true; break; }
            if (!(ps & 1)) und = true;
          }
          if (sup) { st[r] = 1 | 16; continue; }
          if (und) { unsigned int j = atomicAdd(&s_cnt[cur^1],1u); act[cur^1][j] = (unsigned short)r; continue; }
          cs = 3 | 16; st[r] = cs;                // B-kept -> C step now
        }
        // C step (cs has AB_KEPT): all entries, inter>=2
        bool sup = false, und = false;
        for (int k = 1; k <= nAll; ++k) {
          unsigned int e = row[k];
          unsigned char ps = st[e & 0x1FFFu];
          if (e >> 15) {                          // high nbr
            if (ps & 2) { sup = true; break; }    // A-kept always wins
            if (!(ps & 1)) und = true;
          } else {                                // low nbr
            if (!(ps & 1)) { und = true; continue; }  // B-undecided
            if (!(ps & 2)) continue;                  // B-suppressed: not in C
            if (ps & 8) { sup = true; break; }        // C-kept outranking low
            if (!(ps & 4)) und = true;                // C-undecided
          }
        }
        if (sup) st[r] |= 4;
        else if (!und) st[r] |= 12;
        else { unsigned int j = atomicAdd(&s_cnt[cur^1],1u); act[cur^1][j] = (unsigned short)r; }
      }
    }
    __syncthreads();
    if (tid == 0) s_cnt[cur] = 0;
    cur ^= 1;
    __syncthreads();
  }
  __syncthreads();

  // ---- collect final keeps (order irrelevant)
  for (int i = tid; i < M; i += 1024) {
    unsigned char s0 = st[i];
    bool keep = (s0 & 16) ? ((s0 & 8) != 0) : ((s0 & 2) != 0);
    if (keep) {
      unsigned int j = atomicAdd(&s_k, 1u);
      if (j < KCAP) {
        unsigned int pos = list[i];
        unsigned int sb = __float_as_uint(scores[i]);
        skeys[j] = (((unsigned long long)(0xFFFFFFFFu - sb)) << 32) | (unsigned long long)pos;
      }
    }
  }
  __syncthreads();
  unsigned int K = min(s_k, (unsigned int)KCAP);

  // ---- rank-by-count (keys distinct since pos distinct), write rows
  for (unsigned int i = tid; i < K; i += 1024) {
    unsigned long long key = skeys[i];
    unsigned int rank = 0;
    for (unsigned int q = 0; q < K; ++q) rank += (skeys[q] < key) ? 1u : 0u;
    if ((int)rank < nrows) {
      unsigned int pos = (unsigned int)(key & 0xFFFFFFFFu);
      float s = __uint_as_float(0xFFFFFFFFu - (unsigned int)(key >> 32));
      float fx = (float)(pos & 1023), fy = (float)(pos >> 10);
      out[rank*5 + 0] = fx - 2.0f;
      out[rank*5 + 1] = fy - 2.0f;
      out[rank*5 + 2] = fx + 2.0f;
      out[rank*5 + 3] = fy + 2.0f;
      out[rank*5 + 4] = s;
    }
  }
}

extern "C" void kernel_launch(void* const* d_in, const int* in_sizes, int n_in,
                              void* d_out, int out_size, void* d_ws, size_t ws_size,
                              hipStream_t stream) {
  const float* x1 = (const float*)d_in[0];
  const float* x2 = (const float*)d_in[1];
  const float* x3 = (const float*)d_in[2];
  char* ws = (char*)d_ws;
  float* rmap = (float*)ws;                                   // 4MB
  float* Bmap = (float*)(ws + (4u << 20));                    // 4MB
  unsigned int* map = (unsigned int*)(ws + (8u << 20));       // 4MB
  unsigned int* mm  = (unsigned int*)(ws + (12u << 20));      // 64B
  unsigned int* list = (unsigned int*)(ws + (12u << 20) + 4096u);        // 32KB
  float* scores = (float*)(ws + (12u << 20) + (64u << 10));              // 32KB
  unsigned short* adj = (unsigned short*)(ws + (12u << 20) + (128u << 10)); // 768KB
  float2* pmm = (float2*)(ws + (13u << 20));                  // 8KB
  float* pconv = (float*)(ws + (13u << 20) + (16u << 10));    // 2KB
  float* out = (float*)d_out;

  hipMemsetAsync(mm, 0, 64, stream);
  k_resid<<<NPIX/4/256, 256, 0, stream>>>((const float4*)x1, (const float4*)x2,
                                          (const float4*)x3, (float4*)rmap, pmm, mm);
  dim3 gc(GW/TW, GH/TH);
  k_conv<<<gc, 256, 0, stream>>>(rmap, Bmap, pconv, mm);
  k_cand<<<NPIX/4/256, 256, 0, stream>>>((const float4*)Bmap, (uint4*)map, list, scores, mm);
  k_final<<<1, 1024, 0, stream>>>(list, scores, map, mm, adj, out, out_size / 5);
}

// Round 9
// 255.095 us; speedup vs baseline: 1.1503x; 1.1503x over previous
//
#include <hip/hip_runtime.h>
#include <stdint.h>

#define GW 1024
#define GH 1024
#define NPIX (GW*GH)
#define CAP 8192        // max candidates (list/adj capacity)
#define KCAP 4096       // max final keeps held for output ordering
#define ADJ_STRIDE 48   // u16: [0]=n3|n<<6|high<<12, [1..n]= nid | nbrHigh<<15
#define TW 128
#define TH 16
// mm: [0]=cand count [1]=rmin [2]=rmax [3]=bmax [8]=ticket_resid [9]=ticket_conv

// residual map + per-block min/max partials + last-block tail reduction
__global__ __launch_bounds__(256) void k_resid(const float4* __restrict__ x1,
                        const float4* __restrict__ x2,
                        const float4* __restrict__ x3, float4* __restrict__ r,
                        float2* __restrict__ pmm, unsigned int* __restrict__ mm) {
  const int N4 = NPIX / 4;
  int t = blockIdx.x * blockDim.x + threadIdx.x;
  float4 s1 = make_float4(0.f,0.f,0.f,0.f);
  float4 s2 = make_float4(0.f,0.f,0.f,0.f);
#pragma unroll
  for (int c = 0; c < 8; ++c) {
    float4 a = x1[c*N4 + t];
    float4 b = x2[c*N4 + t];
    float4 d = x3[c*N4 + t];
    s1.x += fabsf(a.x-b.x); s1.y += fabsf(a.y-b.y);
    s1.z += fabsf(a.z-b.z); s1.w += fabsf(a.w-b.w);
    s2.x += fabsf(b.x-d.x); s2.y += fabsf(b.y-d.y);
    s2.z += fabsf(b.z-d.z); s2.w += fabsf(b.w-d.w);
  }
  float4 rv = make_float4((s1.x+s2.x)*0.5f, (s1.y+s2.y)*0.5f,
                          (s1.z+s2.z)*0.5f, (s1.w+s2.w)*0.5f);
  r[t] = rv;
  float mn = fminf(fminf(rv.x,rv.y), fminf(rv.z,rv.w));
  float mx = fmaxf(fmaxf(rv.x,rv.y), fmaxf(rv.z,rv.w));
#pragma unroll
  for (int o = 32; o > 0; o >>= 1) {
    mn = fminf(mn, __shfl_down(mn, o));
    mx = fmaxf(mx, __shfl_down(mx, o));
  }
  __shared__ float smn[4], smx[4];
  __shared__ bool isLast;
  int wid = threadIdx.x >> 6;
  if ((threadIdx.x & 63) == 0) { smn[wid] = mn; smx[wid] = mx; }
  __syncthreads();
  if (threadIdx.x == 0) {
    float a = fminf(fminf(smn[0], smn[1]), fminf(smn[2], smn[3]));
    float b = fmaxf(fmaxf(smx[0], smx[1]), fmaxf(smx[2], smx[3]));
    pmm[blockIdx.x] = make_float2(a, b);
    __threadfence();
    unsigned int tk = atomicAdd(&mm[8], 1u);
    isLast = (tk == gridDim.x - 1);
  }
  __syncthreads();
  if (isLast) {
    __threadfence();
    int tid = threadIdx.x;
    float2 p = pmm[tid];
    mn = p.x; mx = p.y;
#pragma unroll
    for (int i = 1; i < 4; ++i) {
      float2 q = pmm[tid + 256*i];
      mn = fminf(mn, q.x); mx = fmaxf(mx, q.y);
    }
#pragma unroll
    for (int o = 32; o > 0; o >>= 1) {
      mn = fminf(mn, __shfl_down(mn, o));
      mx = fmaxf(mx, __shfl_down(mx, o));
    }
    if ((tid & 63) == 0) { smn[tid>>6] = mn; smx[tid>>6] = mx; }
    __syncthreads();
    if (tid == 0) {
      float a = fminf(fminf(smn[0], smn[1]), fminf(smn[2], smn[3]));
      float b = fmaxf(fmaxf(smx[0], smx[1]), fmaxf(smx[2], smx[3]));
      mm[1] = __float_as_uint(a);
      mm[2] = __float_as_uint(b);
    }
  }
}

// fused normalize + y-interp + x-interp over TWxTH tiles with halo in LDS.
// per-output arithmetic identical to the separate convy/convx kernels.
__global__ __launch_bounds__(256) void k_conv(const float* __restrict__ r,
                        float* __restrict__ B, float* __restrict__ pconv,
                        unsigned int* __restrict__ mm) {
  __shared__ float sN[TH+4][TW+4];
  __shared__ float sA[TH][TW+4];
  __shared__ float smx[4];
  __shared__ bool isLast;
  int x0 = blockIdx.x * TW, y0 = blockIdx.y * TH;
  int tid = threadIdx.x;
  float rmin = __uint_as_float(mm[1]);
  float denom = __uint_as_float(mm[2]) - rmin + 1e-6f;
  const float offs[4] = {-1.5f, -0.5f, 0.5f, 1.5f};
  // stage + normalize (TH+4)x(TW+4) (edge rows/cols duplicated via clamp)
  for (int i = tid; i < (TH+4)*(TW+4); i += 256) {
    int row = i / (TW+4), col = i - row*(TW+4);
    int gy = min(max(y0 - 2 + row, 0), GH-1);
    int gx = min(max(x0 - 2 + col, 0), GW-1);
    sN[row][col] = (r[gy*GW + gx] - rmin) / denom;
  }
  __syncthreads();
  // A tile: y-taps, absolute-y weights (exact _interp1d semantics)
  for (int i = tid; i < TH*(TW+4); i += 256) {
    int ty = i / (TW+4), c0 = i - ty*(TW+4);
    int y = y0 + ty;
    float a = 0.f, b = 0.f;
#pragma unroll
    for (int k = 0; k < 4; ++k) {
      float c = (float)y + offs[k];
      bool valid = (c >= -1.0f) && (c <= (float)GH);
      float cc = fminf(fmaxf(c, 0.0f), (float)(GH - 1));
      int lo = (int)floorf(cc);
      int hi = min(lo + 1, GH - 1);
      float frac = cc - (float)lo;
      float w0 = valid ? 1.0f - frac : 0.0f;
      float w1 = valid ? frac : 0.0f;
      a += sN[lo - (y0-2)][c0] * w0;
      b += sN[hi - (y0-2)][c0] * w1;
    }
    sA[ty][c0] = a + b;
  }
  __syncthreads();
  // B: x-taps; thread -> column x0+(tid&127), rows (tid>>7)*8 .. +7
  int tx = tid & 127;
  int tyb = (tid >> 7) * 8;
  int x = x0 + tx;
  int xl[4], xh[4]; float w0x[4], w1x[4];
#pragma unroll
  for (int k = 0; k < 4; ++k) {
    float c = (float)x + offs[k];
    bool valid = (c >= -1.0f) && (c <= (float)GW);
    float cc = fminf(fmaxf(c, 0.0f), (float)(GW - 1));
    int lo = (int)floorf(cc);
    int hi = min(lo + 1, GW - 1);
    float frac = cc - (float)lo;
    w0x[k] = valid ? 1.0f - frac : 0.0f;
    w1x[k] = valid ? frac : 0.0f;
    xl[k] = lo - (x0-2); xh[k] = hi - (x0-2);
  }
  float mxv = 0.0f;   // B >= 0 always
#pragma unroll
  for (int q = 0; q < 8; ++q) {
    int ty = tyb + q;
    float a = 0.f, b = 0.f;
#pragma unroll
    for (int k = 0; k < 4; ++k) {
      a += sA[ty][xl[k]] * w0x[k];
      b += sA[ty][xh[k]] * w1x[k];
    }
    float v = (a + b) * 0.0625f;   // /16 exact
    B[(size_t)(y0+ty)*GW + x] = v;
    mxv = fmaxf(mxv, v);
  }
#pragma unroll
  for (int o = 32; o > 0; o >>= 1) mxv = fmaxf(mxv, __shfl_down(mxv, o));
  if ((tid & 63) == 0) smx[tid>>6] = mxv;
  __syncthreads();
  int nblk = gridDim.x * gridDim.y;
  int bid = blockIdx.y * gridDim.x + blockIdx.x;
  if (tid == 0) {
    pconv[bid] = fmaxf(fmaxf(smx[0], smx[1]), fmaxf(smx[2], smx[3]));
    __threadfence();
    unsigned int tk = atomicAdd(&mm[9], 1u);
    isLast = (tk == (unsigned int)(nblk - 1));
  }
  __syncthreads();
  if (isLast) {
    __threadfence();
    float mx = pconv[tid];
    mx = fmaxf(mx, pconv[tid + 256]);
#pragma unroll
    for (int o = 32; o > 0; o >>= 1) mx = fmaxf(mx, __shfl_down(mx, o));
    if ((tid & 63) == 0) smx[tid>>6] = mx;
    __syncthreads();
    if (tid == 0)
      mm[3] = __float_as_uint(fmaxf(fmaxf(smx[0], smx[1]), fmaxf(smx[2], smx[3])));
  }
}

// candidate compaction (<=1 atomic per block); ids arbitrary order.
// list[id]=pos, scores[id]=s, map[pos]=id (else ~0)
__global__ void k_cand(const float4* __restrict__ B, uint4* __restrict__ map,
                       unsigned int* __restrict__ list, float* __restrict__ scores,
                       unsigned int* __restrict__ mm) {
  int t = blockIdx.x * 256 + threadIdx.x;
  int tid = threadIdx.x;
  float bmax = __uint_as_float(mm[3]);
  float dv = bmax + 1e-6f;
  float4 b = B[t];
  float l[4] = { b.x/dv, b.y/dv, b.z/dv, b.w/dv };
  unsigned int flags = 0; int cnt = 0;
#pragma unroll
  for (int k = 0; k < 4; ++k) {
    float s = l[k];
    if (s > 0.90f && !(s == 0.95f)) { flags |= 1u << k; cnt++; }
  }
  __shared__ unsigned int sscan[256];
  __shared__ unsigned int sbase;
  sscan[tid] = (unsigned int)cnt;
  __syncthreads();
  for (int off = 1; off < 256; off <<= 1) {
    unsigned int v = sscan[tid];
    unsigned int a = (tid >= off) ? sscan[tid - off] : 0u;
    __syncthreads();
    sscan[tid] = v + a;
    __syncthreads();
  }
  if (tid == 255) {
    unsigned int tot = sscan[255];
    if (tot) sbase = atomicAdd(&mm[0], tot);
  }
  __syncthreads();
  unsigned int mv[4] = { ~0u, ~0u, ~0u, ~0u };
  if (flags) {
    unsigned int o = sbase + sscan[tid] - (unsigned int)cnt;
    unsigned int base4 = (unsigned int)t * 4u;
#pragma unroll
    for (int k = 0; k < 4; ++k) {
      if ((flags >> k) & 1u) {
        if (o < CAP) { list[o] = base4 + (unsigned int)k; scores[o] = l[k]; mv[k] = o; }
        o++;
      }
    }
  }
  map[t] = make_uint4(mv[0], mv[1], mv[2], mv[3]);
}

// grid-parallel adjacency: per id, OUTRANKING conflicting neighbor ids
// (inter>=3 entries first so stage-B mask is a prefix).
// priority: score desc, pos asc; scores>=0 so float order == uint-bit order.
__global__ void k_adj(const unsigned int* __restrict__ list,
                      const float* __restrict__ scores,
                      const unsigned int* __restrict__ map,
                      const unsigned int* __restrict__ mm,
                      unsigned short* __restrict__ adj) {
  int r = blockIdx.x * 256 + threadIdx.x;
  int M = (int)min(mm[0], (unsigned int)CAP);
  if (r >= M) return;
  unsigned int pos = list[r];
  float s = scores[r];
  unsigned int sb = __float_as_uint(s);
  unsigned int high = (s > 0.95f) ? 1u : 0u;
  int y = (int)(pos >> 10), x = (int)(pos & 1023);
  int n = 0, n3 = 0;
  unsigned short* row = adj + (size_t)r * ADJ_STRIDE;
#pragma unroll
  for (int pass = 0; pass < 2; ++pass) {
    for (int dy = -3; dy <= 3; ++dy) {
      int ady = dy < 0 ? -dy : dy;
      int wy = 4 - ady;
      int ny = y + dy;
      if ((unsigned)ny >= (unsigned)GH) continue;
      for (int dx = -3; dx <= 3; ++dx) {
        if ((dx | dy) == 0) continue;
        int adx = dx < 0 ? -dx : dx;
        int prod = (4 - adx) * wy;
        if (prod < 2) continue;
        if ((pass == 0) != (prod >= 3)) continue;
        int nx = x + dx;
        if ((unsigned)nx >= (unsigned)GW) continue;
        unsigned int npix = (unsigned int)(ny*GW + nx);
        unsigned int nid = map[npix];
        if (nid == ~0u) continue;
        float ns = scores[nid];
        unsigned int nsb = __float_as_uint(ns);
        if (nsb > sb || (nsb == sb && npix < pos)) {
          unsigned int nh = (ns > 0.95f) ? 1u : 0u;
          row[1 + n] = (unsigned short)(nid | (nh << 15));
          n++;
          if (pass == 0) n3++;
        }
      }
    }
  }
  row[0] = (unsigned short)(n3 | (n << 6) | (high << 12));
}

// single block: fused ABC fixed-point NMS on LDS state + ordered output.
// st bits: 1=AB_DEC 2=AB_KEPT 4=C_DEC 8=C_KEPT 16=LOW
__global__ __launch_bounds__(1024) void k_nms(const unsigned int* __restrict__ list,
                                              const float* __restrict__ scores,
                                              const unsigned short* __restrict__ adj,
                                              const unsigned int* __restrict__ mm,
                                              float* __restrict__ out, int nrows) {
  __shared__ unsigned char st[CAP];
  __shared__ unsigned short act[2][CAP];
  __shared__ unsigned long long skeys[KCAP];
  __shared__ unsigned int s_cnt[2];
  __shared__ unsigned int s_k;
  const int tid = threadIdx.x;
  int M = (int)min(mm[0], (unsigned int)CAP);
  for (int i = tid; i < CAP; i += 1024) st[i] = 0;
  for (int i = tid; i < M; i += 1024) act[0][i] = (unsigned short)i;
  if (tid == 0) { s_cnt[0] = (unsigned int)M; s_cnt[1] = 0; s_k = 0; }
  __syncthreads();

  // ---- one fixed point for stages A (highs), B (lows, n3 prefix), C (chained)
  int cur = 0;
  for (int round = 0; round < CAP; ++round) {
    unsigned int cnt = s_cnt[cur];
    if (cnt == 0) break;
    for (unsigned int i = tid; i < cnt; i += 1024) {
      int r = act[cur][i];
      const unsigned short* row = adj + (size_t)r * ADJ_STRIDE;
      unsigned int hdr = row[0];
      unsigned int high = (hdr >> 12) & 1u;
      int nAll = (int)((hdr >> 6) & 63u);
      int n3 = (int)(hdr & 63u);
      if (high) {
        bool sup = false, und = false;
        for (int k = 1; k <= nAll; ++k) {
          unsigned int e = row[k];
          if (!(e >> 15)) continue;               // same band (high) only
          unsigned char ps = st[e & 0x1FFFu];
          if (ps & 2) { sup = true; break; }
          if (!(ps & 1)) und = true;
        }
        if (sup) st[r] = 1;
        else if (!und) st[r] = 3;
        else { unsigned int j = atomicAdd(&s_cnt[cur^1],1u); act[cur^1][j] = (unsigned short)r; }
      } else {
        unsigned char cs = st[r];
        if (!(cs & 1)) {
          // B step: low-band outranking nbrs within n3 prefix
          bool sup = false, und = false;
          for (int k = 1; k <= n3; ++k) {
            unsigned int e = row[k];
            if (e >> 15) continue;
            unsigned char ps = st[e & 0x1FFFu];
            if (ps & 2) { sup = true; break; }
            if (!(ps & 1)) und = true;
          }
          if (sup) { st[r] = 1 | 16; continue; }
          if (und) { unsigned int j = atomicAdd(&s_cnt[cur^1],1u); act[cur^1][j] = (unsigned short)r; continue; }
          cs = 3 | 16; st[r] = cs;                // B-kept -> C step now
        }
        // C step (cs has AB_KEPT): all entries, inter>=2
        bool sup = false, und = false;
        for (int k = 1; k <= nAll; ++k) {
          unsigned int e = row[k];
          unsigned char ps = st[e & 0x1FFFu];
          if (e >> 15) {                          // high nbr
            if (ps & 2) { sup = true; break; }    // A-kept always wins
            if (!(ps & 1)) und = true;
          } else {                                // low nbr
            if (!(ps & 1)) { und = true; continue; }  // B-undecided
            if (!(ps & 2)) continue;                  // B-suppressed: not in C
            if (ps & 8) { sup = true; break; }        // C-kept outranking low
            if (!(ps & 4)) und = true;                // C-undecided
          }
        }
        if (sup) st[r] |= 4;
        else if (!und) st[r] |= 12;
        else { unsigned int j = atomicAdd(&s_cnt[cur^1],1u); act[cur^1][j] = (unsigned short)r; }
      }
    }
    __syncthreads();
    if (tid == 0) s_cnt[cur] = 0;
    cur ^= 1;
    __syncthreads();
  }
  __syncthreads();

  // ---- collect final keeps (order irrelevant)
  for (int i = tid; i < M; i += 1024) {
    unsigned char s0 = st[i];
    bool keep = (s0 & 16) ? ((s0 & 8) != 0) : ((s0 & 2) != 0);
    if (keep) {
      unsigned int j = atomicAdd(&s_k, 1u);
      if (j < KCAP) {
        unsigned int pos = list[i];
        unsigned int sb = __float_as_uint(scores[i]);
        skeys[j] = (((unsigned long long)(0xFFFFFFFFu - sb)) << 32) | (unsigned long long)pos;
      }
    }
  }
  __syncthreads();
  unsigned int K = min(s_k, (unsigned int)KCAP);

  // ---- rank-by-count (keys distinct since pos distinct), write rows
  for (unsigned int i = tid; i < K; i += 1024) {
    unsigned long long key = skeys[i];
    unsigned int rank = 0;
    for (unsigned int q = 0; q < K; ++q) rank += (skeys[q] < key) ? 1u : 0u;
    if ((int)rank < nrows) {
      unsigned int pos = (unsigned int)(key & 0xFFFFFFFFu);
      float s = __uint_as_float(0xFFFFFFFFu - (unsigned int)(key >> 32));
      float fx = (float)(pos & 1023), fy = (float)(pos >> 10);
      out[rank*5 + 0] = fx - 2.0f;
      out[rank*5 + 1] = fy - 2.0f;
      out[rank*5 + 2] = fx + 2.0f;
      out[rank*5 + 3] = fy + 2.0f;
      out[rank*5 + 4] = s;
    }
  }
}

extern "C" void kernel_launch(void* const* d_in, const int* in_sizes, int n_in,
                              void* d_out, int out_size, void* d_ws, size_t ws_size,
                              hipStream_t stream) {
  const float* x1 = (const float*)d_in[0];
  const float* x2 = (const float*)d_in[1];
  const float* x3 = (const float*)d_in[2];
  char* ws = (char*)d_ws;
  float* rmap = (float*)ws;                                   // 4MB
  float* Bmap = (float*)(ws + (4u << 20));                    // 4MB
  unsigned int* map = (unsigned int*)(ws + (8u << 20));       // 4MB
  unsigned int* mm  = (unsigned int*)(ws + (12u << 20));      // 64B
  unsigned int* list = (unsigned int*)(ws + (12u << 20) + 4096u);        // 32KB
  float* scores = (float*)(ws + (12u << 20) + (64u << 10));              // 32KB
  unsigned short* adj = (unsigned short*)(ws + (12u << 20) + (128u << 10)); // 768KB
  float2* pmm = (float2*)(ws + (13u << 20));                  // 8KB
  float* pconv = (float*)(ws + (13u << 20) + (16u << 10));    // 2KB
  float* out = (float*)d_out;

  hipMemsetAsync(mm, 0, 64, stream);
  k_resid<<<NPIX/4/256, 256, 0, stream>>>((const float4*)x1, (const float4*)x2,
                                          (const float4*)x3, (float4*)rmap, pmm, mm);
  dim3 gc(GW/TW, GH/TH);
  k_conv<<<gc, 256, 0, stream>>>(rmap, Bmap, pconv, mm);
  k_cand<<<NPIX/4/256, 256, 0, stream>>>((const float4*)Bmap, (uint4*)map, list, scores, mm);
  k_adj<<<CAP/256, 256, 0, stream>>>(list, scores, map, mm, adj);
  k_nms<<<1, 1024, 0, stream>>>(list, scores, adj, mm, out, out_size / 5);
}

// Round 10
// 198.817 us; speedup vs baseline: 1.4760x; 1.2831x over previous
//
#include <hip/hip_runtime.h>
#include <stdint.h>

#define GW 1024
#define GH 1024
#define NPIX (GW*GH)
#define CAP 8192        // max candidates (list/adj capacity)
#define KCAP 4096       // max final keeps held for output ordering
#define ADJ_STRIDE 48   // u16: [0]=n3|n<<6|high<<12, [1..n]= nid | nbrHigh<<15
#define TW 128
#define TH 16
#define NCONVBLK ((GW/TW)*(GH/TH))   // 512
// mm: [0]=cand count [1]=rmin [2]=rmax [3]=bmax

// residual map + per-block min/max partials (no fences, no atomics)
__global__ __launch_bounds__(256) void k_resid(const float4* __restrict__ x1,
                        const float4* __restrict__ x2,
                        const float4* __restrict__ x3, float4* __restrict__ r,
                        float2* __restrict__ pmm) {
  const int N4 = NPIX / 4;
  int t = blockIdx.x * blockDim.x + threadIdx.x;
  float4 s1 = make_float4(0.f,0.f,0.f,0.f);
  float4 s2 = make_float4(0.f,0.f,0.f,0.f);
#pragma unroll
  for (int c = 0; c < 8; ++c) {
    float4 a = x1[c*N4 + t];
    float4 b = x2[c*N4 + t];
    float4 d = x3[c*N4 + t];
    s1.x += fabsf(a.x-b.x); s1.y += fabsf(a.y-b.y);
    s1.z += fabsf(a.z-b.z); s1.w += fabsf(a.w-b.w);
    s2.x += fabsf(b.x-d.x); s2.y += fabsf(b.y-d.y);
    s2.z += fabsf(b.z-d.z); s2.w += fabsf(b.w-d.w);
  }
  float4 rv = make_float4((s1.x+s2.x)*0.5f, (s1.y+s2.y)*0.5f,
                          (s1.z+s2.z)*0.5f, (s1.w+s2.w)*0.5f);
  r[t] = rv;
  float mn = fminf(fminf(rv.x,rv.y), fminf(rv.z,rv.w));
  float mx = fmaxf(fmaxf(rv.x,rv.y), fmaxf(rv.z,rv.w));
#pragma unroll
  for (int o = 32; o > 0; o >>= 1) {
    mn = fminf(mn, __shfl_down(mn, o));
    mx = fmaxf(mx, __shfl_down(mx, o));
  }
  __shared__ float smn[4], smx[4];
  int wid = threadIdx.x >> 6;
  if ((threadIdx.x & 63) == 0) { smn[wid] = mn; smx[wid] = mx; }
  __syncthreads();
  if (threadIdx.x == 0) {
    float a = fminf(fminf(smn[0], smn[1]), fminf(smn[2], smn[3]));
    float b = fmaxf(fmaxf(smx[0], smx[1]), fmaxf(smx[2], smx[3]));
    pmm[blockIdx.x] = make_float2(a, b);
  }
}

// 1 block: reduce 1024 block partials -> rmin/rmax
__global__ __launch_bounds__(1024) void k_reduce1(const float2* __restrict__ pmm,
                                                  unsigned int* __restrict__ mm) {
  int t = threadIdx.x;
  float2 p = pmm[t];
  float mn = p.x, mx = p.y;
#pragma unroll
  for (int o = 32; o > 0; o >>= 1) {
    mn = fminf(mn, __shfl_down(mn, o));
    mx = fmaxf(mx, __shfl_down(mx, o));
  }
  __shared__ float smn[16], smx[16];
  int wid = t >> 6;
  if ((t & 63) == 0) { smn[wid] = mn; smx[wid] = mx; }
  __syncthreads();
  if (t == 0) {
    mn = smn[0]; mx = smx[0];
#pragma unroll
    for (int i = 1; i < 16; ++i) { mn = fminf(mn, smn[i]); mx = fmaxf(mx, smx[i]); }
    mm[1] = __float_as_uint(mn);
    mm[2] = __float_as_uint(mx);
  }
}

// fused normalize + y-interp + x-interp over TWxTH tiles with halo in LDS.
// per-output arithmetic identical to the separate convy/convx kernels.
__global__ __launch_bounds__(256) void k_conv(const float* __restrict__ r,
                        float* __restrict__ B, float* __restrict__ pconv,
                        const unsigned int* __restrict__ mm) {
  __shared__ float sN[TH+4][TW+4];
  __shared__ float sA[TH][TW+4];
  __shared__ float smx[4];
  int x0 = blockIdx.x * TW, y0 = blockIdx.y * TH;
  int tid = threadIdx.x;
  float rmin = __uint_as_float(mm[1]);
  float denom = __uint_as_float(mm[2]) - rmin + 1e-6f;
  const float offs[4] = {-1.5f, -0.5f, 0.5f, 1.5f};
  // stage + normalize (TH+4)x(TW+4) (edge rows/cols duplicated via clamp)
  for (int i = tid; i < (TH+4)*(TW+4); i += 256) {
    int row = i / (TW+4), col = i - row*(TW+4);
    int gy = min(max(y0 - 2 + row, 0), GH-1);
    int gx = min(max(x0 - 2 + col, 0), GW-1);
    sN[row][col] = (r[gy*GW + gx] - rmin) / denom;
  }
  __syncthreads();
  // A tile: y-taps, absolute-y weights (exact _interp1d semantics)
  for (int i = tid; i < TH*(TW+4); i += 256) {
    int ty = i / (TW+4), c0 = i - ty*(TW+4);
    int y = y0 + ty;
    float a = 0.f, b = 0.f;
#pragma unroll
    for (int k = 0; k < 4; ++k) {
      float c = (float)y + offs[k];
      bool valid = (c >= -1.0f) && (c <= (float)GH);
      float cc = fminf(fmaxf(c, 0.0f), (float)(GH - 1));
      int lo = (int)floorf(cc);
      int hi = min(lo + 1, GH - 1);
      float frac = cc - (float)lo;
      float w0 = valid ? 1.0f - frac : 0.0f;
      float w1 = valid ? frac : 0.0f;
      a += sN[lo - (y0-2)][c0] * w0;
      b += sN[hi - (y0-2)][c0] * w1;
    }
    sA[ty][c0] = a + b;
  }
  __syncthreads();
  // B: x-taps; thread -> column x0+(tid&127), rows (tid>>7)*8 .. +7
  int tx = tid & 127;
  int tyb = (tid >> 7) * 8;
  int x = x0 + tx;
  int xl[4], xh[4]; float w0x[4], w1x[4];
#pragma unroll
  for (int k = 0; k < 4; ++k) {
    float c = (float)x + offs[k];
    bool valid = (c >= -1.0f) && (c <= (float)GW);
    float cc = fminf(fmaxf(c, 0.0f), (float)(GW - 1));
    int lo = (int)floorf(cc);
    int hi = min(lo + 1, GW - 1);
    float frac = cc - (float)lo;
    w0x[k] = valid ? 1.0f - frac : 0.0f;
    w1x[k] = valid ? frac : 0.0f;
    xl[k] = lo - (x0-2); xh[k] = hi - (x0-2);
  }
  float mxv = 0.0f;   // B >= 0 always (weights>=0, normalized r>=0)
#pragma unroll
  for (int q = 0; q < 8; ++q) {
    int ty = tyb + q;
    float a = 0.f, b = 0.f;
#pragma unroll
    for (int k = 0; k < 4; ++k) {
      a += sA[ty][xl[k]] * w0x[k];
      b += sA[ty][xh[k]] * w1x[k];
    }
    float v = (a + b) * 0.0625f;   // /16 exact
    B[(size_t)(y0+ty)*GW + x] = v;
    mxv = fmaxf(mxv, v);
  }
#pragma unroll
  for (int o = 32; o > 0; o >>= 1) mxv = fmaxf(mxv, __shfl_down(mxv, o));
  if ((tid & 63) == 0) smx[tid>>6] = mxv;
  __syncthreads();
  if (tid == 0) {
    int bid = blockIdx.y * gridDim.x + blockIdx.x;
    pconv[bid] = fmaxf(fmaxf(smx[0], smx[1]), fmaxf(smx[2], smx[3]));
  }
}

// 1 block: reduce NCONVBLK tile maxima -> bmax; zero candidate counter
__global__ __launch_bounds__(1024) void k_reduce2(const float* __restrict__ pconv,
                                                  unsigned int* __restrict__ mm) {
  int t = threadIdx.x;
  float mx = (t < NCONVBLK) ? pconv[t] : 0.0f;   // B >= 0
#pragma unroll
  for (int o = 32; o > 0; o >>= 1) mx = fmaxf(mx, __shfl_down(mx, o));
  __shared__ float smx[16];
  int wid = t >> 6;
  if ((t & 63) == 0) smx[wid] = mx;
  __syncthreads();
  if (t == 0) {
    mx = smx[0];
#pragma unroll
    for (int i = 1; i < 16; ++i) mx = fmaxf(mx, smx[i]);
    mm[3] = __float_as_uint(mx);
    mm[0] = 0u;   // candidate count
  }
}

// candidate compaction (<=1 atomic per block); ids arbitrary order.
// list[id]=pos, scores[id]=s, map[pos]=id (else ~0)
__global__ void k_cand(const float4* __restrict__ B, uint4* __restrict__ map,
                       unsigned int* __restrict__ list, float* __restrict__ scores,
                       unsigned int* __restrict__ mm) {
  int t = blockIdx.x * 256 + threadIdx.x;
  int tid = threadIdx.x;
  float bmax = __uint_as_float(mm[3]);
  float dv = bmax + 1e-6f;
  float4 b = B[t];
  float l[4] = { b.x/dv, b.y/dv, b.z/dv, b.w/dv };
  unsigned int flags = 0; int cnt = 0;
#pragma unroll
  for (int k = 0; k < 4; ++k) {
    float s = l[k];
    if (s > 0.90f && !(s == 0.95f)) { flags |= 1u << k; cnt++; }
  }
  __shared__ unsigned int sscan[256];
  __shared__ unsigned int sbase;
  sscan[tid] = (unsigned int)cnt;
  __syncthreads();
  for (int off = 1; off < 256; off <<= 1) {
    unsigned int v = sscan[tid];
    unsigned int a = (tid >= off) ? sscan[tid - off] : 0u;
    __syncthreads();
    sscan[tid] = v + a;
    __syncthreads();
  }
  if (tid == 255) {
    unsigned int tot = sscan[255];
    if (tot) sbase = atomicAdd(&mm[0], tot);
  }
  __syncthreads();
  unsigned int mv[4] = { ~0u, ~0u, ~0u, ~0u };
  if (flags) {
    unsigned int o = sbase + sscan[tid] - (unsigned int)cnt;
    unsigned int base4 = (unsigned int)t * 4u;
#pragma unroll
    for (int k = 0; k < 4; ++k) {
      if ((flags >> k) & 1u) {
        if (o < CAP) { list[o] = base4 + (unsigned int)k; scores[o] = l[k]; mv[k] = o; }
        o++;
      }
    }
  }
  map[t] = make_uint4(mv[0], mv[1], mv[2], mv[3]);
}

// grid-parallel adjacency: per id, OUTRANKING conflicting neighbor ids
// (inter>=3 entries first so stage-B mask is a prefix).
// priority: score desc, pos asc; scores>=0 so float order == uint-bit order.
__global__ void k_adj(const unsigned int* __restrict__ list,
                      const float* __restrict__ scores,
                      const unsigned int* __restrict__ map,
                      const unsigned int* __restrict__ mm,
                      unsigned short* __restrict__ adj) {
  int r = blockIdx.x * 256 + threadIdx.x;
  int M = (int)min(mm[0], (unsigned int)CAP);
  if (r >= M) return;
  unsigned int pos = list[r];
  float s = scores[r];
  unsigned int sb = __float_as_uint(s);
  unsigned int high = (s > 0.95f) ? 1u : 0u;
  int y = (int)(pos >> 10), x = (int)(pos & 1023);
  int n = 0, n3 = 0;
  unsigned short* row = adj + (size_t)r * ADJ_STRIDE;
#pragma unroll
  for (int pass = 0; pass < 2; ++pass) {
    for (int dy = -3; dy <= 3; ++dy) {
      int ady = dy < 0 ? -dy : dy;
      int wy = 4 - ady;
      int ny = y + dy;
      if ((unsigned)ny >= (unsigned)GH) continue;
      for (int dx = -3; dx <= 3; ++dx) {
        if ((dx | dy) == 0) continue;
        int adx = dx < 0 ? -dx : dx;
        int prod = (4 - adx) * wy;
        if (prod < 2) continue;
        if ((pass == 0) != (prod >= 3)) continue;
        int nx = x + dx;
        if ((unsigned)nx >= (unsigned)GW) continue;
        unsigned int npix = (unsigned int)(ny*GW + nx);
        unsigned int nid = map[npix];
        if (nid == ~0u) continue;
        float ns = scores[nid];
        unsigned int nsb = __float_as_uint(ns);
        if (nsb > sb || (nsb == sb && npix < pos)) {
          unsigned int nh = (ns > 0.95f) ? 1u : 0u;
          row[1 + n] = (unsigned short)(nid | (nh << 15));
          n++;
          if (pass == 0) n3++;
        }
      }
    }
  }
  row[0] = (unsigned short)(n3 | (n << 6) | (high << 12));
}

// single block: fused ABC fixed-point NMS on LDS state + ordered output.
// st bits: 1=AB_DEC 2=AB_KEPT 4=C_DEC 8=C_KEPT 16=LOW
__global__ __launch_bounds__(1024) void k_nms(const unsigned int* __restrict__ list,
                                              const float* __restrict__ scores,
                                              const unsigned short* __restrict__ adj,
                                              const unsigned int* __restrict__ mm,
                                              float* __restrict__ out, int nrows) {
  __shared__ unsigned char st[CAP];
  __shared__ unsigned short act[2][CAP];
  __shared__ unsigned long long skeys[KCAP];
  __shared__ unsigned int s_cnt[2];
  __shared__ unsigned int s_k;
  const int tid = threadIdx.x;
  int M = (int)min(mm[0], (unsigned int)CAP);
  for (int i = tid; i < CAP; i += 1024) st[i] = 0;
  for (int i = tid; i < M; i += 1024) act[0][i] = (unsigned short)i;
  if (tid == 0) { s_cnt[0] = (unsigned int)M; s_cnt[1] = 0; s_k = 0; }
  __syncthreads();

  // ---- one fixed point for stages A (highs), B (lows, n3 prefix), C (chained)
  int cur = 0;
  for (int round = 0; round < CAP; ++round) {
    unsigned int cnt = s_cnt[cur];
    if (cnt == 0) break;
    for (unsigned int i = tid; i < cnt; i += 1024) {
      int r = act[cur][i];
      const unsigned short* row = adj + (size_t)r * ADJ_STRIDE;
      unsigned int hdr = row[0];
      unsigned int high = (hdr >> 12) & 1u;
      int nAll = (int)((hdr >> 6) & 63u);
      int n3 = (int)(hdr & 63u);
      if (high) {
        bool sup = false, und = false;
        for (int k = 1; k <= nAll; ++k) {
          unsigned int e = row[k];
          if (!(e >> 15)) continue;               // same band (high) only
          unsigned char ps = st[e & 0x1FFFu];
          if (ps & 2) { sup = true; break; }
          if (!(ps & 1)) und = true;
        }
        if (sup) st[r] = 1;
        else if (!und) st[r] = 3;
        else { unsigned int j = atomicAdd(&s_cnt[cur^1],1u); act[cur^1][j] = (unsigned short)r; }
      } else {
        unsigned char cs = st[r];
        if (!(cs & 1)) {
          // B step: low-band outranking nbrs within n3 prefix
          bool sup = false, und = false;
          for (int k = 1; k <= n3; ++k) {
            unsigned int e = row[k];
            if (e >> 15) continue;
            unsigned char ps = st[e & 0x1FFFu];
            if (ps & 2) { sup = true; break; }
            if (!(ps & 1)) und = true;
          }
          if (sup) { st[r] = 1 | 16; continue; }
          if (und) { unsigned int j = atomicAdd(&s_cnt[cur^1],1u); act[cur^1][j] = (unsigned short)r; continue; }
          cs = 3 | 16; st[r] = cs;                // B-kept -> C step now
        }
        // C step (cs has AB_KEPT): all entries, inter>=2
        bool sup = false, und = false;
        for (int k = 1; k <= nAll; ++k) {
          unsigned int e = row[k];
          unsigned char ps = st[e & 0x1FFFu];
          if (e >> 15) {                          // high nbr
            if (ps & 2) { sup = true; break; }    // A-kept always wins
            if (!(ps & 1)) und = true;
          } else {                                // low nbr
            if (!(ps & 1)) { und = true; continue; }  // B-undecided
            if (!(ps & 2)) continue;                  // B-suppressed: not in C
            if (ps & 8) { sup = true; break; }        // C-kept outranking low
            if (!(ps & 4)) und = true;                // C-undecided
          }
        }
        if (sup) st[r] |= 4;
        else if (!und) st[r] |= 12;
        else { unsigned int j = atomicAdd(&s_cnt[cur^1],1u); act[cur^1][j] = (unsigned short)r; }
      }
    }
    __syncthreads();
    if (tid == 0) s_cnt[cur] = 0;
    cur ^= 1;
    __syncthreads();
  }
  __syncthreads();

  // ---- collect final keeps (order irrelevant)
  for (int i = tid; i < M; i += 1024) {
    unsigned char s0 = st[i];
    bool keep = (s0 & 16) ? ((s0 & 8) != 0) : ((s0 & 2) != 0);
    if (keep) {
      unsigned int j = atomicAdd(&s_k, 1u);
      if (j < KCAP) {
        unsigned int pos = list[i];
        unsigned int sb = __float_as_uint(scores[i]);
        skeys[j] = (((unsigned long long)(0xFFFFFFFFu - sb)) << 32) | (unsigned long long)pos;
      }
    }
  }
  __syncthreads();
  unsigned int K = min(s_k, (unsigned int)KCAP);

  // ---- rank-by-count (keys distinct since pos distinct), write rows
  for (unsigned int i = tid; i < K; i += 1024) {
    unsigned long long key = skeys[i];
    unsigned int rank = 0;
    for (unsigned int q = 0; q < K; ++q) rank += (skeys[q] < key) ? 1u : 0u;
    if ((int)rank < nrows) {
      unsigned int pos = (unsigned int)(key & 0xFFFFFFFFu);
      float s = __uint_as_float(0xFFFFFFFFu - (unsigned int)(key >> 32));
      float fx = (float)(pos & 1023), fy = (float)(pos >> 10);
      out[rank*5 + 0] = fx - 2.0f;
      out[rank*5 + 1] = fy - 2.0f;
      out[rank*5 + 2] = fx + 2.0f;
      out[rank*5 + 3] = fy + 2.0f;
      out[rank*5 + 4] = s;
    }
  }
}

extern "C" void kernel_launch(void* const* d_in, const int* in_sizes, int n_in,
                              void* d_out, int out_size, void* d_ws, size_t ws_size,
                              hipStream_t stream) {
  const float* x1 = (const float*)d_in[0];
  const float* x2 = (const float*)d_in[1];
  const float* x3 = (const float*)d_in[2];
  char* ws = (char*)d_ws;
  float* rmap = (float*)ws;                                   // 4MB
  float* Bmap = (float*)(ws + (4u << 20));                    // 4MB
  unsigned int* map = (unsigned int*)(ws + (8u << 20));       // 4MB
  unsigned int* mm  = (unsigned int*)(ws + (12u << 20));      // 64B
  unsigned int* list = (unsigned int*)(ws + (12u << 20) + 4096u);        // 32KB
  float* scores = (float*)(ws + (12u << 20) + (64u << 10));              // 32KB
  unsigned short* adj = (unsigned short*)(ws + (12u << 20) + (128u << 10)); // 768KB
  float2* pmm = (float2*)(ws + (13u << 20));                  // 8KB
  float* pconv = (float*)(ws + (13u << 20) + (16u << 10));    // 2KB
  float* out = (float*)d_out;

  k_resid<<<NPIX/4/256, 256, 0, stream>>>((const float4*)x1, (const float4*)x2,
                                          (const float4*)x3, (float4*)rmap, pmm);
  k_reduce1<<<1, 1024, 0, stream>>>(pmm, mm);
  dim3 gc(GW/TW, GH/TH);
  k_conv<<<gc, 256, 0, stream>>>(rmap, Bmap, pconv, mm);
  k_reduce2<<<1, 1024, 0, stream>>>(pconv, mm);
  k_cand<<<NPIX/4/256, 256, 0, stream>>>((const float4*)Bmap, (uint4*)map, list, scores, mm);
  k_adj<<<CAP/256, 256, 0, stream>>>(list, scores, map, mm, adj);
  k_nms<<<1, 1024, 0, stream>>>(list, scores, adj, mm, out, out_size / 5);
}